// Round 1
// baseline (1439.203 us; speedup 1.0000x reference)
//
#include <hip/hip_runtime.h>

#define N_NODES 100000
#define N_EDGES 1600000

// ---------------- helpers ----------------
__device__ inline float4 f4fma(float a, float4 w, float4 acc) {
  acc.x = fmaf(a, w.x, acc.x);
  acc.y = fmaf(a, w.y, acc.y);
  acc.z = fmaf(a, w.z, acc.z);
  acc.w = fmaf(a, w.w, acc.w);
  return acc;
}

// ---------------- degree histogram ----------------
__global__ void k_count(const int* __restrict__ src_i, const int* __restrict__ dst_i,
                        const int* __restrict__ src_b, const int* __restrict__ dst_b,
                        int* cnt_so_i, int* cnt_di_i, int* cnt_so_b, int* cnt_di_b) {
  int e = blockIdx.x * 256 + threadIdx.x;
  if (e < N_EDGES) {
    atomicAdd(&cnt_so_i[src_i[e]], 1);
    atomicAdd(&cnt_di_i[dst_i[e]], 1);
  } else if (e < 2 * N_EDGES) {
    int k = e - N_EDGES;
    atomicAdd(&cnt_so_b[src_b[k]], 1);
    atomicAdd(&cnt_di_b[dst_b[k]], 1);
  }
}

// ---------------- exclusive scan of in-degree counts (one block per relation) ----------------
__global__ __launch_bounds__(1024) void k_scan(
    const int* __restrict__ cnt_a, int* __restrict__ off_a, int* __restrict__ cur_a,
    const int* __restrict__ cnt_c, int* __restrict__ off_c, int* __restrict__ cur_c) {
  const int* cnt = (blockIdx.x == 0) ? cnt_a : cnt_c;
  int* off = (blockIdx.x == 0) ? off_a : off_c;
  int* cur = (blockIdx.x == 0) ? cur_a : cur_c;

  __shared__ int wsum[16];
  __shared__ int s_run;
  const int tid = threadIdx.x;
  const int lane = tid & 63;
  const int wid = tid >> 6;
  if (tid == 0) s_run = 0;

  for (int base = 0; base < N_NODES; base += 1024) {
    int i = base + tid;
    int v = (i < N_NODES) ? cnt[i] : 0;
    int x = v;
#pragma unroll
    for (int d = 1; d < 64; d <<= 1) {
      int t = __shfl_up(x, d);
      if (lane >= d) x += t;
    }
    if (lane == 63) wsum[wid] = x;
    __syncthreads();
    if (tid == 0) {
      int s = s_run;
#pragma unroll
      for (int w = 0; w < 16; ++w) { int t = wsum[w]; wsum[w] = s; s += t; }
      s_run = s;
    }
    __syncthreads();
    int excl = wsum[wid] + x - v;
    if (i < N_NODES) { off[i] = excl; cur[i] = excl; }
    __syncthreads();  // protect wsum before next tile overwrites
  }
  if (tid == 0) off[N_NODES] = s_run;
}

// ---------------- inverse-sqrt degrees (clip at 1) ----------------
__global__ void k_deg(const int* __restrict__ c0, const int* __restrict__ c1,
                      const int* __restrict__ c2, const int* __restrict__ c3,
                      float* d0, float* d1, float* d2, float* d3) {
  int i = blockIdx.x * 256 + threadIdx.x;
  if (i < N_NODES) {
    d0[i] = rsqrtf((float)max(c0[i], 1));
    d1[i] = rsqrtf((float)max(c1[i], 1));
    d2[i] = rsqrtf((float)max(c2[i], 1));
    d3[i] = rsqrtf((float)max(c3[i], 1));
  }
}

// ---------------- CSR fill (counting-sort scatter) ----------------
__global__ void k_fill(const int* __restrict__ src_i, const int* __restrict__ dst_i,
                       const int* __restrict__ src_b, const int* __restrict__ dst_b,
                       int* cur_i, int* cur_b, int* es_i, int* es_b) {
  int e = blockIdx.x * 256 + threadIdx.x;
  if (e < N_EDGES) {
    int p = atomicAdd(&cur_i[dst_i[e]], 1);
    es_i[p] = src_i[e];
  } else if (e < 2 * N_EDGES) {
    int k = e - N_EDGES;
    int p = atomicAdd(&cur_b[dst_b[k]], 1);
    es_b[p] = src_b[k];
  }
}

// ---------------- GEMM: C[row] = rowscale[row] * (A[row] @ W), 128x128 W ----------------
// Block: 256 threads, 64 rows x 64 cols per block. grid = (ceil(N/64), 2).
__global__ __launch_bounds__(256) void k_gemm_rs(
    const float* __restrict__ A, const float* __restrict__ W,
    const float* __restrict__ rowscale, float* __restrict__ C) {
  __shared__ float shW[128 * 64];  // 32 KB: W[k][cb..cb+64)
  __shared__ float shA[64 * 128];  // 32 KB: A[rb..rb+64)[k]
  const int tid = threadIdx.x;
  const int rb = blockIdx.x * 64;
  const int cb = blockIdx.y * 64;

  // stage W column slab
  for (int idx = tid; idx < 128 * 16; idx += 256) {
    int r = idx >> 4, c4 = idx & 15;
    *(float4*)&shW[r * 64 + c4 * 4] = *(const float4*)&W[r * 128 + cb + c4 * 4];
  }
  // stage A row slab (guard tail rows)
  for (int idx = tid; idx < 64 * 32; idx += 256) {
    int r = idx >> 5, c4 = idx & 31;
    float4 v = make_float4(0.f, 0.f, 0.f, 0.f);
    if (rb + r < N_NODES) v = *(const float4*)&A[(size_t)(rb + r) * 128 + c4 * 4];
    *(float4*)&shA[r * 128 + c4 * 4] = v;
  }
  __syncthreads();

  const int tx = tid & 15;   // 16 lanes x 4 cols = 64 cols
  const int ty = tid >> 4;   // 16 groups x 4 rows = 64 rows
  float4 acc[4];
#pragma unroll
  for (int r = 0; r < 4; ++r) acc[r] = make_float4(0.f, 0.f, 0.f, 0.f);

  for (int k = 0; k < 128; k += 4) {
    float4 w0 = *(const float4*)&shW[(k + 0) * 64 + tx * 4];
    float4 w1 = *(const float4*)&shW[(k + 1) * 64 + tx * 4];
    float4 w2 = *(const float4*)&shW[(k + 2) * 64 + tx * 4];
    float4 w3 = *(const float4*)&shW[(k + 3) * 64 + tx * 4];
#pragma unroll
    for (int r = 0; r < 4; ++r) {
      float4 a = *(const float4*)&shA[(ty * 4 + r) * 128 + k];
      acc[r] = f4fma(a.x, w0, acc[r]);
      acc[r] = f4fma(a.y, w1, acc[r]);
      acc[r] = f4fma(a.z, w2, acc[r]);
      acc[r] = f4fma(a.w, w3, acc[r]);
    }
  }

#pragma unroll
  for (int r = 0; r < 4; ++r) {
    int row = rb + ty * 4 + r;
    if (row < N_NODES) {
      float s = rowscale[row];
      float4 o = make_float4(acc[r].x * s, acc[r].y * s, acc[r].z * s, acc[r].w * s);
      *(float4*)&C[(size_t)row * 128 + cb + tx * 4] = o;
    }
  }
}

// ---------------- SpMM (CSR gather) + epilogue ----------------
// MODE 0: out = relu(agg*dsi + b); MODE 1: out += relu(agg*dsi + b); MODE 2: out = agg*dsi + b
template <int MODE>
__global__ __launch_bounds__(128) void k_spmm(
    const float* __restrict__ XW, const int* __restrict__ off,
    const int* __restrict__ srcs, const float* __restrict__ dsi,
    const float* __restrict__ bias, float* __restrict__ out) {
  const int n = blockIdx.x;
  const int t = threadIdx.x;
  const int e0 = off[n];
  const int e1 = off[n + 1];
  float acc = 0.f;
  for (int e = e0; e < e1; ++e) {
    int s = srcs[e];
    acc += XW[(size_t)s * 128 + t];
  }
  float y = fmaf(acc, dsi[n], bias[t]);
  if (MODE != 2) y = fmaxf(y, 0.f);
  if (MODE == 1)
    out[(size_t)n * 128 + t] += y;
  else
    out[(size_t)n * 128 + t] = y;
}

// ---------------- host ----------------
extern "C" void kernel_launch(void* const* d_in, const int* in_sizes, int n_in,
                              void* d_out, int out_size, void* d_ws, size_t ws_size,
                              hipStream_t stream) {
  const float* x    = (const float*)d_in[0];
  const int* src_i  = (const int*)d_in[1];
  const int* dst_i  = (const int*)d_in[2];
  const int* src_b  = (const int*)d_in[3];
  const int* dst_b  = (const int*)d_in[4];
  const float* W1_i = (const float*)d_in[5];
  const float* b1_i = (const float*)d_in[6];
  const float* W1_b = (const float*)d_in[7];
  const float* b1_b = (const float*)d_in[8];
  const float* W2   = (const float*)d_in[9];
  const float* b2   = (const float*)d_in[10];
  float* out = (float*)d_out;

  char* ws = (char*)d_ws;
  size_t o = 0;
  auto alloc = [&](size_t bytes) {
    char* p = ws + o;
    o += (bytes + 255) & ~(size_t)255;
    return p;
  };
  int* cnt_so_i = (int*)alloc(N_NODES * 4);
  int* cnt_di_i = (int*)alloc(N_NODES * 4);
  int* cnt_so_b = (int*)alloc(N_NODES * 4);
  int* cnt_di_b = (int*)alloc(N_NODES * 4);
  size_t cnt_span = o;  // bytes to zero (the four count arrays incl. padding)
  float* dso_i = (float*)alloc(N_NODES * 4);
  float* dsi_i = (float*)alloc(N_NODES * 4);
  float* dso_b = (float*)alloc(N_NODES * 4);
  float* dsi_b = (float*)alloc(N_NODES * 4);
  int* off_i = (int*)alloc((N_NODES + 1) * 4);
  int* off_b = (int*)alloc((N_NODES + 1) * 4);
  int* cur_i = (int*)alloc(N_NODES * 4);
  int* cur_b = (int*)alloc(N_NODES * 4);
  int* es_i = (int*)alloc((size_t)N_EDGES * 4);
  int* es_b = (int*)alloc((size_t)N_EDGES * 4);
  float* bufXW = (float*)alloc((size_t)N_NODES * 128 * 4);
  (void)ws_size; (void)in_sizes; (void)n_in; (void)out_size;

  // 1) zero degree counters
  hipMemsetAsync(d_ws, 0, cnt_span, stream);
  // 2) histogram degrees (both relations)
  k_count<<<dim3((2 * N_EDGES + 255) / 256), dim3(256), 0, stream>>>(
      src_i, dst_i, src_b, dst_b, cnt_so_i, cnt_di_i, cnt_so_b, cnt_di_b);
  // 3) exclusive scan of in-degrees -> CSR row offsets (+ cursor copies)
  k_scan<<<2, 1024, 0, stream>>>(cnt_di_i, off_i, cur_i, cnt_di_b, off_b, cur_b);
  // 4) inverse-sqrt degrees
  k_deg<<<(N_NODES + 255) / 256, dim3(256), 0, stream>>>(
      cnt_so_i, cnt_di_i, cnt_so_b, cnt_di_b, dso_i, dsi_i, dso_b, dsi_b);
  // 5) CSR fill
  k_fill<<<dim3((2 * N_EDGES + 255) / 256), dim3(256), 0, stream>>>(
      src_i, dst_i, src_b, dst_b, cur_i, cur_b, es_i, es_b);

  dim3 ggrid((N_NODES + 63) / 64, 2);
  // conv1 / interacts: XW = dso_i ⊙ (x @ W1_i); h = relu(A_i XW * dsi_i + b1_i)
  k_gemm_rs<<<ggrid, dim3(256), 0, stream>>>(x, W1_i, dso_i, bufXW);
  k_spmm<0><<<N_NODES, 128, 0, stream>>>(bufXW, off_i, es_i, dsi_i, b1_i, out);
  // conv1 / behave: h += relu(A_b (dso_b ⊙ xW1_b) * dsi_b + b1_b)
  k_gemm_rs<<<ggrid, dim3(256), 0, stream>>>(x, W1_b, dso_b, bufXW);
  k_spmm<1><<<N_NODES, 128, 0, stream>>>(bufXW, off_b, es_b, dsi_b, b1_b, out);
  // conv2 / interacts (no relu): out = A_i (dso_i ⊙ h W2) * dsi_i + b2
  k_gemm_rs<<<ggrid, dim3(256), 0, stream>>>(out, W2, dso_i, bufXW);
  k_spmm<2><<<N_NODES, 128, 0, stream>>>(bufXW, off_i, es_i, dsi_i, b2, out);
}

// Round 2
// 1087.452 us; speedup vs baseline: 1.3235x; 1.3235x over previous
//
#include <hip/hip_runtime.h>

#define N_NODES 100000
#define N_EDGES 1600000
#define NT 98        // ceil(N_NODES / 1024) scan tiles
#define SWEEPS 16
#define SLICE ((N_NODES + SWEEPS - 1) / SWEEPS)  // 6250

// ---------------- helpers ----------------
__device__ inline float4 f4fma(float a, float4 w, float4 acc) {
  acc.x = fmaf(a, w.x, acc.x);
  acc.y = fmaf(a, w.y, acc.y);
  acc.z = fmaf(a, w.z, acc.z);
  acc.w = fmaf(a, w.w, acc.w);
  return acc;
}

// ---------------- degree histogram (int4-vectorized, grid.y = relation) ----------------
__global__ __launch_bounds__(256) void k_count(
    const int* __restrict__ src_i, const int* __restrict__ dst_i,
    const int* __restrict__ src_b, const int* __restrict__ dst_b,
    int* cnt_so_i, int* cnt_di_i, int* cnt_so_b, int* cnt_di_b) {
  const int t = blockIdx.x * 256 + threadIdx.x;  // quad index
  if (t >= N_EDGES / 4) return;
  const int rel = blockIdx.y;
  const int* src = rel ? src_b : src_i;
  const int* dst = rel ? dst_b : dst_i;
  int* cso = rel ? cnt_so_b : cnt_so_i;
  int* cdi = rel ? cnt_di_b : cnt_di_i;
  int4 s4 = ((const int4*)src)[t];
  int4 d4 = ((const int4*)dst)[t];
  atomicAdd(&cso[s4.x], 1); atomicAdd(&cso[s4.y], 1);
  atomicAdd(&cso[s4.z], 1); atomicAdd(&cso[s4.w], 1);
  atomicAdd(&cdi[d4.x], 1); atomicAdd(&cdi[d4.y], 1);
  atomicAdd(&cdi[d4.z], 1); atomicAdd(&cdi[d4.w], 1);
}

// ---------------- scan phase 1: per-tile exclusive scan + tile totals ----------------
// grid (NT, 2), 256 threads, 4 elements/thread (tile = 1024)
__global__ __launch_bounds__(256) void k_scan1(
    const int* __restrict__ cnt_i, const int* __restrict__ cnt_b,
    int* __restrict__ off_i, int* __restrict__ off_b, int* __restrict__ tsum) {
  const int rel = blockIdx.y;
  const int* cnt = rel ? cnt_b : cnt_i;
  int* off = rel ? off_b : off_i;
  const int tid = threadIdx.x;
  const int i0 = blockIdx.x * 1024 + tid * 4;
  int v[4];
#pragma unroll
  for (int k = 0; k < 4; ++k) v[k] = (i0 + k < N_NODES) ? cnt[i0 + k] : 0;
  int tl = v[0] + v[1] + v[2] + v[3];
  const int lane = tid & 63, wid = tid >> 6;
  int x = tl;
#pragma unroll
  for (int d = 1; d < 64; d <<= 1) {
    int t = __shfl_up(x, d);
    if (lane >= d) x += t;
  }
  __shared__ int wsum[4];
  if (lane == 63) wsum[wid] = x;
  __syncthreads();
  int wb = 0;
#pragma unroll
  for (int w = 0; w < 4; ++w)
    if (w < wid) wb += wsum[w];
  int run = wb + x - tl;  // exclusive prefix of this thread within tile
#pragma unroll
  for (int k = 0; k < 4; ++k) {
    if (i0 + k < N_NODES) off[i0 + k] = run;
    run += v[k];
  }
  if (tid == 255) tsum[rel * NT + blockIdx.x] = wb + x;  // tile total
}

// ---------------- scan phase 2: exclusive scan of tile totals (1 block) ----------------
__global__ __launch_bounds__(256) void k_scan2(int* __restrict__ tsum) {
  __shared__ int a[256], b[256];
  const int t = threadIdx.x;
  for (int rel = 0; rel < 2; ++rel) {
    a[t] = (t < NT) ? tsum[rel * NT + t] : 0;
    __syncthreads();
    int* p = a;
    int* q = b;
    for (int d = 1; d < 256; d <<= 1) {
      q[t] = (t >= d) ? p[t - d] + p[t] : p[t];
      __syncthreads();
      int* tmp = p; p = q; q = tmp;
    }
    int excl = (t == 0) ? 0 : p[t - 1];
    if (t < NT) tsum[rel * NT + t] = excl;
    __syncthreads();
  }
}

// ---------------- scan phase 3: add tile bases, emit off + cur ----------------
__global__ __launch_bounds__(256) void k_scan3(
    const int* __restrict__ tsum, int* __restrict__ off_i, int* __restrict__ off_b,
    int* __restrict__ cur_i, int* __restrict__ cur_b) {
  const int rel = blockIdx.y;
  int* off = rel ? off_b : off_i;
  int* cur = rel ? cur_b : cur_i;
  const int tb = tsum[rel * NT + blockIdx.x];
  const int i0 = blockIdx.x * 1024 + threadIdx.x * 4;
#pragma unroll
  for (int k = 0; k < 4; ++k) {
    if (i0 + k < N_NODES) {
      int val = off[i0 + k] + tb;
      off[i0 + k] = val;
      cur[i0 + k] = val;
    }
  }
  if (blockIdx.x == 0 && threadIdx.x == 0) off[N_NODES] = N_EDGES;
}

// ---------------- inverse-sqrt degrees (clip at 1) ----------------
__global__ void k_deg(const int* __restrict__ c0, const int* __restrict__ c1,
                      const int* __restrict__ c2, const int* __restrict__ c3,
                      float* d0, float* d1, float* d2, float* d3) {
  int i = blockIdx.x * 256 + threadIdx.x;
  if (i < N_NODES) {
    d0[i] = rsqrtf((float)max(c0[i], 1));
    d1[i] = rsqrtf((float)max(c1[i], 1));
    d2[i] = rsqrtf((float)max(c2[i], 1));
    d3[i] = rsqrtf((float)max(c3[i], 1));
  }
}

// ---------------- CSR fill: dst-sliced sweeps for write locality ----------------
// grid (edge_quads/256, 2 relations, SWEEPS). Each edge handled exactly once
// (by the z-slice containing its dst) — slicing is a pure locality heuristic,
// correct under any block scheduling. Scatter window per slice ~= 400 KB.
__global__ __launch_bounds__(256) void k_fill(
    const int* __restrict__ src_i, const int* __restrict__ dst_i,
    const int* __restrict__ src_b, const int* __restrict__ dst_b,
    int* cur_i, int* cur_b, int* es_i, int* es_b) {
  const int t = blockIdx.x * 256 + threadIdx.x;  // quad index
  if (t >= N_EDGES / 4) return;
  const int rel = blockIdx.y;
  const int lo = blockIdx.z * SLICE;
  const int hi = lo + SLICE;
  const int* src = rel ? src_b : src_i;
  const int* dst = rel ? dst_b : dst_i;
  int* cur = rel ? cur_b : cur_i;
  int* es = rel ? es_b : es_i;
  int4 d4 = ((const int4*)dst)[t];
  int4 s4;
  bool any = (d4.x >= lo && d4.x < hi) || (d4.y >= lo && d4.y < hi) ||
             (d4.z >= lo && d4.z < hi) || (d4.w >= lo && d4.w < hi);
  if (!any) return;
  s4 = ((const int4*)src)[t];
  if (d4.x >= lo && d4.x < hi) es[atomicAdd(&cur[d4.x], 1)] = s4.x;
  if (d4.y >= lo && d4.y < hi) es[atomicAdd(&cur[d4.y], 1)] = s4.y;
  if (d4.z >= lo && d4.z < hi) es[atomicAdd(&cur[d4.z], 1)] = s4.z;
  if (d4.w >= lo && d4.w < hi) es[atomicAdd(&cur[d4.w], 1)] = s4.w;
}

// ---------------- GEMM: C[row] = rowscale[row] * (A[row] @ W), 128x128 W ----------------
__global__ __launch_bounds__(256) void k_gemm_rs(
    const float* __restrict__ A, const float* __restrict__ W,
    const float* __restrict__ rowscale, float* __restrict__ C) {
  __shared__ float shW[128 * 64];
  __shared__ float shA[64 * 128];
  const int tid = threadIdx.x;
  const int rb = blockIdx.x * 64;
  const int cb = blockIdx.y * 64;

  for (int idx = tid; idx < 128 * 16; idx += 256) {
    int r = idx >> 4, c4 = idx & 15;
    *(float4*)&shW[r * 64 + c4 * 4] = *(const float4*)&W[r * 128 + cb + c4 * 4];
  }
  for (int idx = tid; idx < 64 * 32; idx += 256) {
    int r = idx >> 5, c4 = idx & 31;
    float4 v = make_float4(0.f, 0.f, 0.f, 0.f);
    if (rb + r < N_NODES) v = *(const float4*)&A[(size_t)(rb + r) * 128 + c4 * 4];
    *(float4*)&shA[r * 128 + c4 * 4] = v;
  }
  __syncthreads();

  const int tx = tid & 15;
  const int ty = tid >> 4;
  float4 acc[4];
#pragma unroll
  for (int r = 0; r < 4; ++r) acc[r] = make_float4(0.f, 0.f, 0.f, 0.f);

  for (int k = 0; k < 128; k += 4) {
    float4 w0 = *(const float4*)&shW[(k + 0) * 64 + tx * 4];
    float4 w1 = *(const float4*)&shW[(k + 1) * 64 + tx * 4];
    float4 w2 = *(const float4*)&shW[(k + 2) * 64 + tx * 4];
    float4 w3 = *(const float4*)&shW[(k + 3) * 64 + tx * 4];
#pragma unroll
    for (int r = 0; r < 4; ++r) {
      float4 a = *(const float4*)&shA[(ty * 4 + r) * 128 + k];
      acc[r] = f4fma(a.x, w0, acc[r]);
      acc[r] = f4fma(a.y, w1, acc[r]);
      acc[r] = f4fma(a.z, w2, acc[r]);
      acc[r] = f4fma(a.w, w3, acc[r]);
    }
  }

#pragma unroll
  for (int r = 0; r < 4; ++r) {
    int row = rb + ty * 4 + r;
    if (row < N_NODES) {
      float s = rowscale[row];
      float4 o = make_float4(acc[r].x * s, acc[r].y * s, acc[r].z * s, acc[r].w * s);
      *(float4*)&C[(size_t)row * 128 + cb + tx * 4] = o;
    }
  }
}

// ---------------- SpMM v2: 32 threads/node (float4 cols), 8 nodes/block ----------------
// MODE 0: out = relu(agg*dsi + b); MODE 1: out += relu(agg*dsi + b); MODE 2: out = agg*dsi + b
template <int MODE>
__global__ __launch_bounds__(256) void k_spmm(
    const float* __restrict__ XW, const int* __restrict__ off,
    const int* __restrict__ srcs, const float* __restrict__ dsi,
    const float* __restrict__ bias, float* __restrict__ out) {
  const int g = threadIdx.x >> 5;  // node group within block
  const int l = threadIdx.x & 31;  // lane within group: 4 cols each
  const int n = blockIdx.x * 8 + g;
  if (n >= N_NODES) return;
  const int e0 = off[n];
  const int e1 = off[n + 1];
  const float4* Xv = (const float4*)XW;  // row stride = 32 float4
  float4 acc = make_float4(0.f, 0.f, 0.f, 0.f);
  for (int eb = e0; eb < e1; eb += 32) {
    int idx = eb + l;
    int s = (idx < e1) ? srcs[idx] : 0;  // coalesced batch load of srcs
    int cnt = min(32, e1 - eb);
#pragma unroll 4
    for (int j = 0; j < cnt; ++j) {
      int sj = __shfl(s, j, 32);  // broadcast edge j's src within the group
      float4 v = Xv[(size_t)sj * 32 + l];
      acc.x += v.x; acc.y += v.y; acc.z += v.z; acc.w += v.w;
    }
  }
  const float dn = dsi[n];
  float4 b4 = ((const float4*)bias)[l];
  float4 y;
  y.x = fmaf(acc.x, dn, b4.x);
  y.y = fmaf(acc.y, dn, b4.y);
  y.z = fmaf(acc.z, dn, b4.z);
  y.w = fmaf(acc.w, dn, b4.w);
  if (MODE != 2) {
    y.x = fmaxf(y.x, 0.f); y.y = fmaxf(y.y, 0.f);
    y.z = fmaxf(y.z, 0.f); y.w = fmaxf(y.w, 0.f);
  }
  float4* ov = (float4*)out;
  size_t oi = (size_t)n * 32 + l;
  if (MODE == 1) {
    float4 p = ov[oi];
    y.x += p.x; y.y += p.y; y.z += p.z; y.w += p.w;
  }
  ov[oi] = y;
}

// ---------------- host ----------------
extern "C" void kernel_launch(void* const* d_in, const int* in_sizes, int n_in,
                              void* d_out, int out_size, void* d_ws, size_t ws_size,
                              hipStream_t stream) {
  const float* x    = (const float*)d_in[0];
  const int* src_i  = (const int*)d_in[1];
  const int* dst_i  = (const int*)d_in[2];
  const int* src_b  = (const int*)d_in[3];
  const int* dst_b  = (const int*)d_in[4];
  const float* W1_i = (const float*)d_in[5];
  const float* b1_i = (const float*)d_in[6];
  const float* W1_b = (const float*)d_in[7];
  const float* b1_b = (const float*)d_in[8];
  const float* W2   = (const float*)d_in[9];
  const float* b2   = (const float*)d_in[10];
  float* out = (float*)d_out;

  char* ws = (char*)d_ws;
  size_t o = 0;
  auto alloc = [&](size_t bytes) {
    char* p = ws + o;
    o += (bytes + 255) & ~(size_t)255;
    return p;
  };
  int* cnt_so_i = (int*)alloc(N_NODES * 4);
  int* cnt_di_i = (int*)alloc(N_NODES * 4);
  int* cnt_so_b = (int*)alloc(N_NODES * 4);
  int* cnt_di_b = (int*)alloc(N_NODES * 4);
  size_t cnt_span = o;  // bytes to zero
  float* dso_i = (float*)alloc(N_NODES * 4);
  float* dsi_i = (float*)alloc(N_NODES * 4);
  float* dso_b = (float*)alloc(N_NODES * 4);
  float* dsi_b = (float*)alloc(N_NODES * 4);
  int* off_i = (int*)alloc((N_NODES + 1) * 4);
  int* off_b = (int*)alloc((N_NODES + 1) * 4);
  int* cur_i = (int*)alloc(N_NODES * 4);
  int* cur_b = (int*)alloc(N_NODES * 4);
  int* tsum = (int*)alloc(2 * NT * 4);
  int* es_i = (int*)alloc((size_t)N_EDGES * 4);
  int* es_b = (int*)alloc((size_t)N_EDGES * 4);
  float* bufXW = (float*)alloc((size_t)N_NODES * 128 * 4);
  (void)ws_size; (void)in_sizes; (void)n_in; (void)out_size;

  hipMemsetAsync(d_ws, 0, cnt_span, stream);

  const int eq_blocks = (N_EDGES / 4 + 255) / 256;  // 1563
  k_count<<<dim3(eq_blocks, 2), dim3(256), 0, stream>>>(
      src_i, dst_i, src_b, dst_b, cnt_so_i, cnt_di_i, cnt_so_b, cnt_di_b);

  k_scan1<<<dim3(NT, 2), dim3(256), 0, stream>>>(cnt_di_i, cnt_di_b, off_i, off_b, tsum);
  k_scan2<<<1, 256, 0, stream>>>(tsum);
  k_scan3<<<dim3(NT, 2), dim3(256), 0, stream>>>(tsum, off_i, off_b, cur_i, cur_b);

  k_deg<<<(N_NODES + 255) / 256, dim3(256), 0, stream>>>(
      cnt_so_i, cnt_di_i, cnt_so_b, cnt_di_b, dso_i, dsi_i, dso_b, dsi_b);

  k_fill<<<dim3(eq_blocks, 2, SWEEPS), dim3(256), 0, stream>>>(
      src_i, dst_i, src_b, dst_b, cur_i, cur_b, es_i, es_b);

  dim3 ggrid((N_NODES + 63) / 64, 2);
  const int sgrid = (N_NODES + 7) / 8;  // 12500
  // conv1 / interacts
  k_gemm_rs<<<ggrid, dim3(256), 0, stream>>>(x, W1_i, dso_i, bufXW);
  k_spmm<0><<<sgrid, 256, 0, stream>>>(bufXW, off_i, es_i, dsi_i, b1_i, out);
  // conv1 / behave
  k_gemm_rs<<<ggrid, dim3(256), 0, stream>>>(x, W1_b, dso_b, bufXW);
  k_spmm<1><<<sgrid, 256, 0, stream>>>(bufXW, off_b, es_b, dsi_b, b1_b, out);
  // conv2 / interacts (no relu)
  k_gemm_rs<<<ggrid, dim3(256), 0, stream>>>(out, W2, dso_i, bufXW);
  k_spmm<2><<<sgrid, 256, 0, stream>>>(bufXW, off_i, es_i, dsi_i, b2, out);
}

// Round 3
// 985.553 us; speedup vs baseline: 1.4603x; 1.1034x over previous
//
#include <hip/hip_runtime.h>

#define N_NODES 100000
#define N_EDGES 1600000
#define NT 98        // ceil(N_NODES / 1024) scan tiles
#define XB 8                     // edge chunks
#define SH 8                     // histogram/fill slices
#define HBINS (N_NODES / SH)     // 12500 bins/slice (50 KB LDS)
#define CHUNK (N_EDGES / XB)     // 200000 edges/chunk

// ---------------- helpers ----------------
__device__ inline float4 f4fma(float a, float4 w, float4 acc) {
  acc.x = fmaf(a, w.x, acc.x);
  acc.y = fmaf(a, w.y, acc.y);
  acc.z = fmaf(a, w.z, acc.z);
  acc.w = fmaf(a, w.w, acc.w);
  return acc;
}

// ---------------- sliced LDS histogram: NO global atomics ----------------
// grid (XB, 4 jobs, SH). job: 0=src_i 1=dst_i 2=src_b 3=dst_b.
// part[job][xb][bin] written with plain coalesced stores.
__global__ __launch_bounds__(256) void k_hist(
    const int* __restrict__ src_i, const int* __restrict__ dst_i,
    const int* __restrict__ src_b, const int* __restrict__ dst_b,
    int* __restrict__ part) {
  __shared__ int h[HBINS];
  const int xb = blockIdx.x, job = blockIdx.y, sl = blockIdx.z;
  const int* arr = (job == 0) ? src_i : (job == 1) ? dst_i : (job == 2) ? src_b : dst_b;
  const int lo = sl * HBINS;
  for (int i = threadIdx.x; i < HBINS; i += 256) h[i] = 0;
  __syncthreads();
  const int4* a4 = (const int4*)(arr + xb * CHUNK);
  for (int q = threadIdx.x; q < CHUNK / 4; q += 256) {
    int4 v = a4[q];
    int t;
    t = v.x - lo; if ((unsigned)t < HBINS) atomicAdd(&h[t], 1);
    t = v.y - lo; if ((unsigned)t < HBINS) atomicAdd(&h[t], 1);
    t = v.z - lo; if ((unsigned)t < HBINS) atomicAdd(&h[t], 1);
    t = v.w - lo; if ((unsigned)t < HBINS) atomicAdd(&h[t], 1);
  }
  __syncthreads();
  int* dst = part + (job * XB + xb) * N_NODES + lo;
  for (int i = threadIdx.x; i < HBINS; i += 256) dst[i] = h[i];
}

// ---------------- reduce partials: degrees (+rsqrt) and in-place chunk prefixes ----
__global__ __launch_bounds__(256) void k_hred(
    int* __restrict__ part, int* __restrict__ cnt_di_i, int* __restrict__ cnt_di_b,
    float* __restrict__ dso_i, float* __restrict__ dsi_i,
    float* __restrict__ dso_b, float* __restrict__ dsi_b) {
  const int bin = blockIdx.x * 256 + threadIdx.x;
  if (bin >= N_NODES) return;
  int s;
  // job0: src_i -> out-degree interacts
  s = 0;
#pragma unroll
  for (int xb = 0; xb < XB; ++xb) s += part[(0 * XB + xb) * N_NODES + bin];
  dso_i[bin] = rsqrtf((float)max(s, 1));
  // job1: dst_i -> in-degree interacts; rewrite as exclusive prefix (reservation bases)
  s = 0;
#pragma unroll
  for (int xb = 0; xb < XB; ++xb) {
    int idx = (1 * XB + xb) * N_NODES + bin;
    int v = part[idx];
    part[idx] = s;
    s += v;
  }
  cnt_di_i[bin] = s;
  dsi_i[bin] = rsqrtf((float)max(s, 1));
  // job2: src_b
  s = 0;
#pragma unroll
  for (int xb = 0; xb < XB; ++xb) s += part[(2 * XB + xb) * N_NODES + bin];
  dso_b[bin] = rsqrtf((float)max(s, 1));
  // job3: dst_b -> prefix in place
  s = 0;
#pragma unroll
  for (int xb = 0; xb < XB; ++xb) {
    int idx = (3 * XB + xb) * N_NODES + bin;
    int v = part[idx];
    part[idx] = s;
    s += v;
  }
  cnt_di_b[bin] = s;
  dsi_b[bin] = rsqrtf((float)max(s, 1));
}

// ---------------- scan phase 1: per-tile exclusive scan + tile totals ----------------
__global__ __launch_bounds__(256) void k_scan1(
    const int* __restrict__ cnt_i, const int* __restrict__ cnt_b,
    int* __restrict__ off_i, int* __restrict__ off_b, int* __restrict__ tsum) {
  const int rel = blockIdx.y;
  const int* cnt = rel ? cnt_b : cnt_i;
  int* off = rel ? off_b : off_i;
  const int tid = threadIdx.x;
  const int i0 = blockIdx.x * 1024 + tid * 4;
  int v[4];
#pragma unroll
  for (int k = 0; k < 4; ++k) v[k] = (i0 + k < N_NODES) ? cnt[i0 + k] : 0;
  int tl = v[0] + v[1] + v[2] + v[3];
  const int lane = tid & 63, wid = tid >> 6;
  int x = tl;
#pragma unroll
  for (int d = 1; d < 64; d <<= 1) {
    int t = __shfl_up(x, d);
    if (lane >= d) x += t;
  }
  __shared__ int wsum[4];
  if (lane == 63) wsum[wid] = x;
  __syncthreads();
  int wb = 0;
#pragma unroll
  for (int w = 0; w < 4; ++w)
    if (w < wid) wb += wsum[w];
  int run = wb + x - tl;
#pragma unroll
  for (int k = 0; k < 4; ++k) {
    if (i0 + k < N_NODES) off[i0 + k] = run;
    run += v[k];
  }
  if (tid == 255) tsum[rel * NT + blockIdx.x] = wb + x;
}

// ---------------- scan phase 2: exclusive scan of tile totals (1 block) ----------------
__global__ __launch_bounds__(256) void k_scan2(int* __restrict__ tsum) {
  __shared__ int a[256], b[256];
  const int t = threadIdx.x;
  for (int rel = 0; rel < 2; ++rel) {
    a[t] = (t < NT) ? tsum[rel * NT + t] : 0;
    __syncthreads();
    int* p = a;
    int* q = b;
    for (int d = 1; d < 256; d <<= 1) {
      q[t] = (t >= d) ? p[t - d] + p[t] : p[t];
      __syncthreads();
      int* tmp = p; p = q; q = tmp;
    }
    int excl = (t == 0) ? 0 : p[t - 1];
    if (t < NT) tsum[rel * NT + t] = excl;
    __syncthreads();
  }
}

// ---------------- scan phase 3: add tile bases ----------------
__global__ __launch_bounds__(256) void k_scan3(
    const int* __restrict__ tsum, int* __restrict__ off_i, int* __restrict__ off_b) {
  const int rel = blockIdx.y;
  int* off = rel ? off_b : off_i;
  const int tb = tsum[rel * NT + blockIdx.x];
  const int i0 = blockIdx.x * 1024 + threadIdx.x * 4;
#pragma unroll
  for (int k = 0; k < 4; ++k)
    if (i0 + k < N_NODES) off[i0 + k] += tb;
  if (blockIdx.x == 0 && threadIdx.x == 0) off[N_NODES] = N_EDGES;
}

// ---------------- CSR fill: LDS cursors from exact reservations, NO global atomics ----
// grid (XB, 2 relations, SH). Block (xb, rel, sl) owns dst-slice [lo,hi) of chunk xb;
// its slots are [off[d]+pref[xb][d], +count) — disjoint across chunks by construction.
__global__ __launch_bounds__(256) void k_fill(
    const int* __restrict__ src_i, const int* __restrict__ dst_i,
    const int* __restrict__ src_b, const int* __restrict__ dst_b,
    const int* __restrict__ off_i, const int* __restrict__ off_b,
    const int* __restrict__ part, int* __restrict__ es_i, int* __restrict__ es_b) {
  __shared__ int cur[HBINS];
  const int xb = blockIdx.x, rel = blockIdx.y, sl = blockIdx.z;
  const int* src = rel ? src_b : src_i;
  const int* dst = rel ? dst_b : dst_i;
  const int* off = rel ? off_b : off_i;
  int* es = rel ? es_b : es_i;
  const int lo = sl * HBINS;
  const int* pf = part + ((rel ? 3 : 1) * XB + xb) * N_NODES + lo;
  for (int i = threadIdx.x; i < HBINS; i += 256) cur[i] = off[lo + i] + pf[i];
  __syncthreads();
  const int4* s4p = (const int4*)(src + xb * CHUNK);
  const int4* d4p = (const int4*)(dst + xb * CHUNK);
  for (int q = threadIdx.x; q < CHUNK / 4; q += 256) {
    int4 d = d4p[q];
    int tx = d.x - lo, ty = d.y - lo, tz = d.z - lo, tw = d.w - lo;
    bool ax = (unsigned)tx < HBINS, ay = (unsigned)ty < HBINS,
         az = (unsigned)tz < HBINS, aw = (unsigned)tw < HBINS;
    if (!(ax | ay | az | aw)) continue;
    int4 s = s4p[q];
    if (ax) es[atomicAdd(&cur[tx], 1)] = s.x;
    if (ay) es[atomicAdd(&cur[ty], 1)] = s.y;
    if (az) es[atomicAdd(&cur[tz], 1)] = s.z;
    if (aw) es[atomicAdd(&cur[tw], 1)] = s.w;
  }
}

// ---------------- GEMM: C[row] = rowscale[row] * (A[row] @ W), 128x128 W ----------------
__global__ __launch_bounds__(256) void k_gemm_rs(
    const float* __restrict__ A, const float* __restrict__ W,
    const float* __restrict__ rowscale, float* __restrict__ C) {
  __shared__ float shW[128 * 64];
  __shared__ float shA[64 * 128];
  const int tid = threadIdx.x;
  const int rb = blockIdx.x * 64;
  const int cb = blockIdx.y * 64;

  for (int idx = tid; idx < 128 * 16; idx += 256) {
    int r = idx >> 4, c4 = idx & 15;
    *(float4*)&shW[r * 64 + c4 * 4] = *(const float4*)&W[r * 128 + cb + c4 * 4];
  }
  for (int idx = tid; idx < 64 * 32; idx += 256) {
    int r = idx >> 5, c4 = idx & 31;
    float4 v = make_float4(0.f, 0.f, 0.f, 0.f);
    if (rb + r < N_NODES) v = *(const float4*)&A[(size_t)(rb + r) * 128 + c4 * 4];
    *(float4*)&shA[r * 128 + c4 * 4] = v;
  }
  __syncthreads();

  const int tx = tid & 15;
  const int ty = tid >> 4;
  float4 acc[4];
#pragma unroll
  for (int r = 0; r < 4; ++r) acc[r] = make_float4(0.f, 0.f, 0.f, 0.f);

  for (int k = 0; k < 128; k += 4) {
    float4 w0 = *(const float4*)&shW[(k + 0) * 64 + tx * 4];
    float4 w1 = *(const float4*)&shW[(k + 1) * 64 + tx * 4];
    float4 w2 = *(const float4*)&shW[(k + 2) * 64 + tx * 4];
    float4 w3 = *(const float4*)&shW[(k + 3) * 64 + tx * 4];
#pragma unroll
    for (int r = 0; r < 4; ++r) {
      float4 a = *(const float4*)&shA[(ty * 4 + r) * 128 + k];
      acc[r] = f4fma(a.x, w0, acc[r]);
      acc[r] = f4fma(a.y, w1, acc[r]);
      acc[r] = f4fma(a.z, w2, acc[r]);
      acc[r] = f4fma(a.w, w3, acc[r]);
    }
  }

#pragma unroll
  for (int r = 0; r < 4; ++r) {
    int row = rb + ty * 4 + r;
    if (row < N_NODES) {
      float s = rowscale[row];
      float4 o = make_float4(acc[r].x * s, acc[r].y * s, acc[r].z * s, acc[r].w * s);
      *(float4*)&C[(size_t)row * 128 + cb + tx * 4] = o;
    }
  }
}

// ---------------- SpMM: 32 threads/node (float4 cols), 8 nodes/block ----------------
template <int MODE>
__global__ __launch_bounds__(256) void k_spmm(
    const float* __restrict__ XW, const int* __restrict__ off,
    const int* __restrict__ srcs, const float* __restrict__ dsi,
    const float* __restrict__ bias, float* __restrict__ out) {
  const int g = threadIdx.x >> 5;
  const int l = threadIdx.x & 31;
  const int n = blockIdx.x * 8 + g;
  if (n >= N_NODES) return;
  const int e0 = off[n];
  const int e1 = off[n + 1];
  const float4* Xv = (const float4*)XW;
  float4 acc = make_float4(0.f, 0.f, 0.f, 0.f);
  for (int eb = e0; eb < e1; eb += 32) {
    int idx = eb + l;
    int s = (idx < e1) ? srcs[idx] : 0;
    int cnt = min(32, e1 - eb);
#pragma unroll 4
    for (int j = 0; j < cnt; ++j) {
      int sj = __shfl(s, j, 32);
      float4 v = Xv[(size_t)sj * 32 + l];
      acc.x += v.x; acc.y += v.y; acc.z += v.z; acc.w += v.w;
    }
  }
  const float dn = dsi[n];
  float4 b4 = ((const float4*)bias)[l];
  float4 y;
  y.x = fmaf(acc.x, dn, b4.x);
  y.y = fmaf(acc.y, dn, b4.y);
  y.z = fmaf(acc.z, dn, b4.z);
  y.w = fmaf(acc.w, dn, b4.w);
  if (MODE != 2) {
    y.x = fmaxf(y.x, 0.f); y.y = fmaxf(y.y, 0.f);
    y.z = fmaxf(y.z, 0.f); y.w = fmaxf(y.w, 0.f);
  }
  float4* ov = (float4*)out;
  size_t oi = (size_t)n * 32 + l;
  if (MODE == 1) {
    float4 p = ov[oi];
    y.x += p.x; y.y += p.y; y.z += p.z; y.w += p.w;
  }
  ov[oi] = y;
}

// ---------------- host ----------------
extern "C" void kernel_launch(void* const* d_in, const int* in_sizes, int n_in,
                              void* d_out, int out_size, void* d_ws, size_t ws_size,
                              hipStream_t stream) {
  const float* x    = (const float*)d_in[0];
  const int* src_i  = (const int*)d_in[1];
  const int* dst_i  = (const int*)d_in[2];
  const int* src_b  = (const int*)d_in[3];
  const int* dst_b  = (const int*)d_in[4];
  const float* W1_i = (const float*)d_in[5];
  const float* b1_i = (const float*)d_in[6];
  const float* W1_b = (const float*)d_in[7];
  const float* b1_b = (const float*)d_in[8];
  const float* W2   = (const float*)d_in[9];
  const float* b2   = (const float*)d_in[10];
  float* out = (float*)d_out;

  char* ws = (char*)d_ws;
  size_t o = 0;
  auto alloc = [&](size_t bytes) {
    char* p = ws + o;
    o += (bytes + 255) & ~(size_t)255;
    return p;
  };
  float* dso_i = (float*)alloc(N_NODES * 4);
  float* dsi_i = (float*)alloc(N_NODES * 4);
  float* dso_b = (float*)alloc(N_NODES * 4);
  float* dsi_b = (float*)alloc(N_NODES * 4);
  int* cnt_di_i = (int*)alloc(N_NODES * 4);
  int* cnt_di_b = (int*)alloc(N_NODES * 4);
  int* off_i = (int*)alloc((N_NODES + 1) * 4);
  int* off_b = (int*)alloc((N_NODES + 1) * 4);
  int* tsum = (int*)alloc(2 * NT * 4);
  int* es_i = (int*)alloc((size_t)N_EDGES * 4);
  int* es_b = (int*)alloc((size_t)N_EDGES * 4);
  // union region: part (4*XB*N = 12.8 MB) is dead before the first GEMM,
  // so bufXW (51.2 MB) aliases it — stream ordering makes this safe.
  char* uni = alloc((size_t)N_NODES * 128 * 4);
  int* part = (int*)uni;
  float* bufXW = (float*)uni;
  (void)ws_size; (void)in_sizes; (void)n_in; (void)out_size;

  k_hist<<<dim3(XB, 4, SH), dim3(256), 0, stream>>>(src_i, dst_i, src_b, dst_b, part);
  k_hred<<<(N_NODES + 255) / 256, dim3(256), 0, stream>>>(
      part, cnt_di_i, cnt_di_b, dso_i, dsi_i, dso_b, dsi_b);
  k_scan1<<<dim3(NT, 2), dim3(256), 0, stream>>>(cnt_di_i, cnt_di_b, off_i, off_b, tsum);
  k_scan2<<<1, 256, 0, stream>>>(tsum);
  k_scan3<<<dim3(NT, 2), dim3(256), 0, stream>>>(tsum, off_i, off_b);
  k_fill<<<dim3(XB, 2, SH), dim3(256), 0, stream>>>(
      src_i, dst_i, src_b, dst_b, off_i, off_b, part, es_i, es_b);

  dim3 ggrid((N_NODES + 63) / 64, 2);
  const int sgrid = (N_NODES + 7) / 8;
  // conv1 / interacts
  k_gemm_rs<<<ggrid, dim3(256), 0, stream>>>(x, W1_i, dso_i, bufXW);
  k_spmm<0><<<sgrid, 256, 0, stream>>>(bufXW, off_i, es_i, dsi_i, b1_i, out);
  // conv1 / behave
  k_gemm_rs<<<ggrid, dim3(256), 0, stream>>>(x, W1_b, dso_b, bufXW);
  k_spmm<1><<<sgrid, 256, 0, stream>>>(bufXW, off_b, es_b, dsi_b, b1_b, out);
  // conv2 / interacts (no relu)
  k_gemm_rs<<<ggrid, dim3(256), 0, stream>>>(out, W2, dso_i, bufXW);
  k_spmm<2><<<sgrid, 256, 0, stream>>>(bufXW, off_i, es_i, dsi_i, b2, out);
}

// Round 5
// 643.288 us; speedup vs baseline: 2.2373x; 1.5321x over previous
//
#include <hip/hip_runtime.h>

#define N_NODES 100000
#define N_EDGES 1600000
#define NT 98                    // ceil(N_NODES / 1024) scan tiles
#define XB 32                    // edge chunks
#define CHUNK (N_EDGES / XB)     // 50000 edges/chunk
#define HSH 8                    // histogram slices
#define HBINS (N_NODES / HSH)    // 12500 bins/slice (u16-packed: 25 KB)
#define FSH 16                   // fill slices
#define FBINS (N_NODES / FSH)    // 6250 cursors/slice (25 KB)

// ---------------- helpers ----------------
__device__ inline float4 f4fma(float a, float4 w, float4 acc) {
  acc.x = fmaf(a, w.x, acc.x);
  acc.y = fmaf(a, w.y, acc.y);
  acc.z = fmaf(a, w.z, acc.z);
  acc.w = fmaf(a, w.w, acc.w);
  return acc;
}
__device__ inline unsigned bf16rn(float f) {  // round-to-nearest-even bf16
  unsigned u = __float_as_uint(f);
  return (u + 0x7FFFu + ((u >> 16) & 1u)) >> 16;
}
__device__ inline float bflo(unsigned w) { return __uint_as_float(w << 16); }
__device__ inline float bfhi(unsigned w) { return __uint_as_float(w & 0xFFFF0000u); }

// ---------------- sliced LDS histogram, u16-packed counters, NO global atomics ----
// grid (XB, 4 jobs, HSH). job: 0=src_i 1=dst_i 2=src_b 3=dst_b.
__global__ __launch_bounds__(256) void k_hist(
    const int* __restrict__ src_i, const int* __restrict__ dst_i,
    const int* __restrict__ src_b, const int* __restrict__ dst_b,
    int* __restrict__ part) {
  __shared__ unsigned h32[HBINS / 2];
  const int xb = blockIdx.x, job = blockIdx.y, sl = blockIdx.z;
  const int* arr = (job == 0) ? src_i : (job == 1) ? dst_i : (job == 2) ? src_b : dst_b;
  const int lo = sl * HBINS;
  for (int i = threadIdx.x; i < HBINS / 2; i += 256) h32[i] = 0;
  __syncthreads();
  const int4* a4 = (const int4*)(arr + xb * CHUNK);
  for (int q = threadIdx.x; q < CHUNK / 4; q += 256) {
    int4 v = a4[q];
    int t;
    t = v.x - lo; if ((unsigned)t < HBINS) atomicAdd(&h32[t >> 1], 1u << ((t & 1) * 16));
    t = v.y - lo; if ((unsigned)t < HBINS) atomicAdd(&h32[t >> 1], 1u << ((t & 1) * 16));
    t = v.z - lo; if ((unsigned)t < HBINS) atomicAdd(&h32[t >> 1], 1u << ((t & 1) * 16));
    t = v.w - lo; if ((unsigned)t < HBINS) atomicAdd(&h32[t >> 1], 1u << ((t & 1) * 16));
  }
  __syncthreads();
  int* dst = part + (job * XB + xb) * N_NODES + lo;
  for (int i = threadIdx.x; i < HBINS; i += 256)
    dst[i] = (h32[i >> 1] >> ((i & 1) * 16)) & 0xFFFFu;
}

// ---------------- reduce partials: degrees (+rsqrt) and in-place chunk prefixes ----
__global__ __launch_bounds__(256) void k_hred(
    int* __restrict__ part, int* __restrict__ cnt_di_i, int* __restrict__ cnt_di_b,
    float* __restrict__ dso_i, float* __restrict__ dsi_i,
    float* __restrict__ dso_b, float* __restrict__ dsi_b) {
  const int bin = blockIdx.x * 256 + threadIdx.x;
  if (bin >= N_NODES) return;
  int s;
  s = 0;
#pragma unroll
  for (int xb = 0; xb < XB; ++xb) s += part[(0 * XB + xb) * N_NODES + bin];
  dso_i[bin] = rsqrtf((float)max(s, 1));
  s = 0;
#pragma unroll
  for (int xb = 0; xb < XB; ++xb) {
    int idx = (1 * XB + xb) * N_NODES + bin;
    int v = part[idx];
    part[idx] = s;
    s += v;
  }
  cnt_di_i[bin] = s;
  dsi_i[bin] = rsqrtf((float)max(s, 1));
  s = 0;
#pragma unroll
  for (int xb = 0; xb < XB; ++xb) s += part[(2 * XB + xb) * N_NODES + bin];
  dso_b[bin] = rsqrtf((float)max(s, 1));
  s = 0;
#pragma unroll
  for (int xb = 0; xb < XB; ++xb) {
    int idx = (3 * XB + xb) * N_NODES + bin;
    int v = part[idx];
    part[idx] = s;
    s += v;
  }
  cnt_di_b[bin] = s;
  dsi_b[bin] = rsqrtf((float)max(s, 1));
}

// ---------------- scan phase 1: per-tile exclusive scan + tile totals ----------------
__global__ __launch_bounds__(256) void k_scan1(
    const int* __restrict__ cnt_i, const int* __restrict__ cnt_b,
    int* __restrict__ off_i, int* __restrict__ off_b, int* __restrict__ tsum) {
  const int rel = blockIdx.y;
  const int* cnt = rel ? cnt_b : cnt_i;
  int* off = rel ? off_b : off_i;
  const int tid = threadIdx.x;
  const int i0 = blockIdx.x * 1024 + tid * 4;
  int v[4];
#pragma unroll
  for (int k = 0; k < 4; ++k) v[k] = (i0 + k < N_NODES) ? cnt[i0 + k] : 0;
  int tl = v[0] + v[1] + v[2] + v[3];
  const int lane = tid & 63, wid = tid >> 6;
  int x = tl;
#pragma unroll
  for (int d = 1; d < 64; d <<= 1) {
    int t = __shfl_up(x, d);
    if (lane >= d) x += t;
  }
  __shared__ int wsum[4];
  if (lane == 63) wsum[wid] = x;
  __syncthreads();
  int wb = 0;
#pragma unroll
  for (int w = 0; w < 4; ++w)
    if (w < wid) wb += wsum[w];
  int run = wb + x - tl;
#pragma unroll
  for (int k = 0; k < 4; ++k) {
    if (i0 + k < N_NODES) off[i0 + k] = run;
    run += v[k];
  }
  if (tid == 255) tsum[rel * NT + blockIdx.x] = wb + x;
}

// ---------------- scan phase 2 ----------------
__global__ __launch_bounds__(256) void k_scan2(int* __restrict__ tsum) {
  __shared__ int a[256], b[256];
  const int t = threadIdx.x;
  for (int rel = 0; rel < 2; ++rel) {
    a[t] = (t < NT) ? tsum[rel * NT + t] : 0;
    __syncthreads();
    int* p = a;
    int* q = b;
    for (int d = 1; d < 256; d <<= 1) {
      q[t] = (t >= d) ? p[t - d] + p[t] : p[t];
      __syncthreads();
      int* tmp = p; p = q; q = tmp;
    }
    int excl = (t == 0) ? 0 : p[t - 1];
    if (t < NT) tsum[rel * NT + t] = excl;
    __syncthreads();
  }
}

// ---------------- scan phase 3 ----------------
__global__ __launch_bounds__(256) void k_scan3(
    const int* __restrict__ tsum, int* __restrict__ off_i, int* __restrict__ off_b) {
  const int rel = blockIdx.y;
  int* off = rel ? off_b : off_i;
  const int tb = tsum[rel * NT + blockIdx.x];
  const int i0 = blockIdx.x * 1024 + threadIdx.x * 4;
#pragma unroll
  for (int k = 0; k < 4; ++k)
    if (i0 + k < N_NODES) off[i0 + k] += tb;
  if (blockIdx.x == 0 && threadIdx.x == 0) off[N_NODES] = N_EDGES;
}

// ---------------- CSR fill: LDS cursors from exact reservations, NO global atomics ----
// grid (XB, 2, FSH). Slots [off[d]+pref[xb][d], +count) are disjoint across chunks.
__global__ __launch_bounds__(256) void k_fill(
    const int* __restrict__ src_i, const int* __restrict__ dst_i,
    const int* __restrict__ src_b, const int* __restrict__ dst_b,
    const int* __restrict__ off_i, const int* __restrict__ off_b,
    const int* __restrict__ part, int* __restrict__ es_i, int* __restrict__ es_b) {
  __shared__ int cur[FBINS];
  const int xb = blockIdx.x, rel = blockIdx.y, sl = blockIdx.z;
  const int* src = rel ? src_b : src_i;
  const int* dst = rel ? dst_b : dst_i;
  const int* off = rel ? off_b : off_i;
  int* es = rel ? es_b : es_i;
  const int lo = sl * FBINS;
  const int* pf = part + ((rel ? 3 : 1) * XB + xb) * N_NODES + lo;
  for (int i = threadIdx.x; i < FBINS; i += 256) cur[i] = off[lo + i] + pf[i];
  __syncthreads();
  const int4* s4p = (const int4*)(src + xb * CHUNK);
  const int4* d4p = (const int4*)(dst + xb * CHUNK);
  for (int q = threadIdx.x; q < CHUNK / 4; q += 256) {
    int4 d = d4p[q];
    int tx = d.x - lo, ty = d.y - lo, tz = d.z - lo, tw = d.w - lo;
    bool ax = (unsigned)tx < FBINS, ay = (unsigned)ty < FBINS,
         az = (unsigned)tz < FBINS, aw = (unsigned)tw < FBINS;
    if (!(ax | ay | az | aw)) continue;
    int4 s = s4p[q];
    if (ax) es[atomicAdd(&cur[tx], 1)] = s.x;
    if (ay) es[atomicAdd(&cur[ty], 1)] = s.y;
    if (az) es[atomicAdd(&cur[tz], 1)] = s.z;
    if (aw) es[atomicAdd(&cur[tw], 1)] = s.w;
  }
}

// ---------------- GEMM: C[row] = bf16( rowscale[row] * (A[row] @ W) ) ----------------
__global__ __launch_bounds__(256) void k_gemm_rs(
    const float* __restrict__ A, const float* __restrict__ W,
    const float* __restrict__ rowscale, unsigned short* __restrict__ C) {
  __shared__ float shW[128 * 64];
  __shared__ float shA[64 * 128];
  const int tid = threadIdx.x;
  const int rb = blockIdx.x * 64;
  const int cb = blockIdx.y * 64;

  for (int idx = tid; idx < 128 * 16; idx += 256) {
    int r = idx >> 4, c4 = idx & 15;
    *(float4*)&shW[r * 64 + c4 * 4] = *(const float4*)&W[r * 128 + cb + c4 * 4];
  }
  for (int idx = tid; idx < 64 * 32; idx += 256) {
    int r = idx >> 5, c4 = idx & 31;
    float4 v = make_float4(0.f, 0.f, 0.f, 0.f);
    if (rb + r < N_NODES) v = *(const float4*)&A[(size_t)(rb + r) * 128 + c4 * 4];
    *(float4*)&shA[r * 128 + c4 * 4] = v;
  }
  __syncthreads();

  const int tx = tid & 15;
  const int ty = tid >> 4;
  float4 acc[4];
#pragma unroll
  for (int r = 0; r < 4; ++r) acc[r] = make_float4(0.f, 0.f, 0.f, 0.f);

  for (int k = 0; k < 128; k += 4) {
    float4 w0 = *(const float4*)&shW[(k + 0) * 64 + tx * 4];
    float4 w1 = *(const float4*)&shW[(k + 1) * 64 + tx * 4];
    float4 w2 = *(const float4*)&shW[(k + 2) * 64 + tx * 4];
    float4 w3 = *(const float4*)&shW[(k + 3) * 64 + tx * 4];
#pragma unroll
    for (int r = 0; r < 4; ++r) {
      float4 a = *(const float4*)&shA[(ty * 4 + r) * 128 + k];
      acc[r] = f4fma(a.x, w0, acc[r]);
      acc[r] = f4fma(a.y, w1, acc[r]);
      acc[r] = f4fma(a.z, w2, acc[r]);
      acc[r] = f4fma(a.w, w3, acc[r]);
    }
  }

#pragma unroll
  for (int r = 0; r < 4; ++r) {
    int row = rb + ty * 4 + r;
    if (row < N_NODES) {
      float s = rowscale[row];
      unsigned w0 = bf16rn(acc[r].x * s) | (bf16rn(acc[r].y * s) << 16);
      unsigned w1 = bf16rn(acc[r].z * s) | (bf16rn(acc[r].w * s) << 16);
      uint2 o = make_uint2(w0, w1);
      *(uint2*)&C[(size_t)row * 128 + cb + tx * 4] = o;
    }
  }
}

// ---------------- SpMM: 16 lanes/node (uint4 = 8 bf16 cols each), 16 nodes/block ----
// MODE 0: out = relu(agg*dsi + b); MODE 1: out += relu(...); MODE 2: out = agg*dsi + b
template <int MODE>
__global__ __launch_bounds__(256) void k_spmm(
    const unsigned short* __restrict__ Xb, const int* __restrict__ off,
    const int* __restrict__ srcs, const float* __restrict__ dsi,
    const float* __restrict__ bias, float* __restrict__ out) {
  const int g = threadIdx.x >> 4;  // node group
  const int l = threadIdx.x & 15;  // lane: 8 cols
  const int n = blockIdx.x * 16 + g;
  if (n >= N_NODES) return;
  const int e0 = off[n];
  const int e1 = off[n + 1];
  const uint4* Xv = (const uint4*)Xb;  // row = 16 uint4
  float a0 = 0.f, a1 = 0.f, a2 = 0.f, a3 = 0.f, a4 = 0.f, a5 = 0.f, a6 = 0.f, a7 = 0.f;
  for (int eb = e0; eb < e1; eb += 16) {
    int idx = eb + l;
    int s = (idx < e1) ? srcs[idx] : 0;
    int cnt = min(16, e1 - eb);
#pragma unroll 4
    for (int j = 0; j < cnt; ++j) {
      int sj = __shfl(s, j, 16);
      uint4 v = Xv[(size_t)sj * 16 + l];
      a0 += bflo(v.x); a1 += bfhi(v.x);
      a2 += bflo(v.y); a3 += bfhi(v.y);
      a4 += bflo(v.z); a5 += bfhi(v.z);
      a6 += bflo(v.w); a7 += bfhi(v.w);
    }
  }
  const float dn = dsi[n];
  float4 b0 = ((const float4*)bias)[l * 2];
  float4 b1 = ((const float4*)bias)[l * 2 + 1];
  float4 y0, y1;
  y0.x = fmaf(a0, dn, b0.x); y0.y = fmaf(a1, dn, b0.y);
  y0.z = fmaf(a2, dn, b0.z); y0.w = fmaf(a3, dn, b0.w);
  y1.x = fmaf(a4, dn, b1.x); y1.y = fmaf(a5, dn, b1.y);
  y1.z = fmaf(a6, dn, b1.z); y1.w = fmaf(a7, dn, b1.w);
  if (MODE != 2) {
    y0.x = fmaxf(y0.x, 0.f); y0.y = fmaxf(y0.y, 0.f);
    y0.z = fmaxf(y0.z, 0.f); y0.w = fmaxf(y0.w, 0.f);
    y1.x = fmaxf(y1.x, 0.f); y1.y = fmaxf(y1.y, 0.f);
    y1.z = fmaxf(y1.z, 0.f); y1.w = fmaxf(y1.w, 0.f);
  }
  float4* ov = (float4*)out;
  size_t oi = (size_t)n * 32 + l * 2;
  if (MODE == 1) {
    float4 p0 = ov[oi], p1 = ov[oi + 1];
    y0.x += p0.x; y0.y += p0.y; y0.z += p0.z; y0.w += p0.w;
    y1.x += p1.x; y1.y += p1.y; y1.z += p1.z; y1.w += p1.w;
  }
  ov[oi] = y0;
  ov[oi + 1] = y1;
}

// ---------------- host ----------------
extern "C" void kernel_launch(void* const* d_in, const int* in_sizes, int n_in,
                              void* d_out, int out_size, void* d_ws, size_t ws_size,
                              hipStream_t stream) {
  const float* x    = (const float*)d_in[0];
  const int* src_i  = (const int*)d_in[1];
  const int* dst_i  = (const int*)d_in[2];
  const int* src_b  = (const int*)d_in[3];
  const int* dst_b  = (const int*)d_in[4];
  const float* W1_i = (const float*)d_in[5];
  const float* b1_i = (const float*)d_in[6];
  const float* W1_b = (const float*)d_in[7];
  const float* b1_b = (const float*)d_in[8];
  const float* W2   = (const float*)d_in[9];
  const float* b2   = (const float*)d_in[10];
  float* out = (float*)d_out;

  char* ws = (char*)d_ws;
  size_t o = 0;
  auto alloc = [&](size_t bytes) {
    char* p = ws + o;
    o += (bytes + 255) & ~(size_t)255;
    return p;
  };
  float* dso_i = (float*)alloc(N_NODES * 4);
  float* dsi_i = (float*)alloc(N_NODES * 4);
  float* dso_b = (float*)alloc(N_NODES * 4);
  float* dsi_b = (float*)alloc(N_NODES * 4);
  int* cnt_di_i = (int*)alloc(N_NODES * 4);
  int* cnt_di_b = (int*)alloc(N_NODES * 4);
  int* off_i = (int*)alloc((N_NODES + 1) * 4);
  int* off_b = (int*)alloc((N_NODES + 1) * 4);
  int* tsum = (int*)alloc(2 * NT * 4);
  int* es_i = (int*)alloc((size_t)N_EDGES * 4);
  int* es_b = (int*)alloc((size_t)N_EDGES * 4);
  // union region: part (4*XB*N*4 = 51.2 MB) is dead before the first GEMM;
  // bufXW (bf16, 25.6 MB) aliases it — stream ordering makes this safe.
  char* uni = alloc((size_t)4 * XB * N_NODES * 4);
  int* part = (int*)uni;
  unsigned short* bufXW = (unsigned short*)uni;
  (void)ws_size; (void)in_sizes; (void)n_in; (void)out_size;

  k_hist<<<dim3(XB, 4, HSH), dim3(256), 0, stream>>>(src_i, dst_i, src_b, dst_b, part);
  k_hred<<<(N_NODES + 255) / 256, dim3(256), 0, stream>>>(
      part, cnt_di_i, cnt_di_b, dso_i, dsi_i, dso_b, dsi_b);
  k_scan1<<<dim3(NT, 2), dim3(256), 0, stream>>>(cnt_di_i, cnt_di_b, off_i, off_b, tsum);
  k_scan2<<<1, 256, 0, stream>>>(tsum);
  k_scan3<<<dim3(NT, 2), dim3(256), 0, stream>>>(tsum, off_i, off_b);
  k_fill<<<dim3(XB, 2, FSH), dim3(256), 0, stream>>>(
      src_i, dst_i, src_b, dst_b, off_i, off_b, part, es_i, es_b);

  dim3 ggrid((N_NODES + 63) / 64, 2);
  const int sgrid = (N_NODES + 15) / 16;
  // conv1 / interacts
  k_gemm_rs<<<ggrid, dim3(256), 0, stream>>>(x, W1_i, dso_i, bufXW);
  k_spmm<0><<<sgrid, 256, 0, stream>>>(bufXW, off_i, es_i, dsi_i, b1_i, out);
  // conv1 / behave
  k_gemm_rs<<<ggrid, dim3(256), 0, stream>>>(x, W1_b, dso_b, bufXW);
  k_spmm<1><<<sgrid, 256, 0, stream>>>(bufXW, off_b, es_b, dsi_b, b1_b, out);
  // conv2 / interacts (no relu)
  k_gemm_rs<<<ggrid, dim3(256), 0, stream>>>(out, W2, dso_i, bufXW);
  k_spmm<2><<<sgrid, 256, 0, stream>>>(bufXW, off_i, es_i, dsi_i, b2, out);
}

// Round 6
// 490.157 us; speedup vs baseline: 2.9362x; 1.3124x over previous
//
#include <hip/hip_runtime.h>
#include <hip/hip_fp16.h>

#define N_NODES 100000
#define N_EDGES 1600000
#define NT 98                    // ceil(N_NODES / 1024) scan tiles
#define XB 32                    // edge chunks
#define CHUNK (N_EDGES / XB)     // 50000 edges/chunk
#define HSH 8                    // histogram slices
#define HBINS (N_NODES / HSH)    // 12500 bins/slice (u16-packed: 25 KB)
#define FSH 16                   // fill slices
#define FBINS (N_NODES / FSH)    // 6250 cursors/slice (25 KB)
#define WT_LD 136                // shw leading dim (halves): 272 B = 17*16 -> aligned, 2-way banks

typedef _Float16 half8_t __attribute__((ext_vector_type(8)));
typedef float f32x4 __attribute__((ext_vector_type(4)));

// ---------------- helpers ----------------
__device__ inline unsigned packh2(float a, float b) {  // low=a, high=b (fp16 rn)
  __half2 h = __floats2half2_rn(a, b);
  return *(unsigned*)&h;
}

// ---------------- sliced LDS histogram, u16-packed counters, NO global atomics ----
// grid (XB, 4 jobs, HSH). job: 0=src_i 1=dst_i 2=src_b 3=dst_b. part is u16.
__global__ __launch_bounds__(256) void k_hist(
    const int* __restrict__ src_i, const int* __restrict__ dst_i,
    const int* __restrict__ src_b, const int* __restrict__ dst_b,
    unsigned short* __restrict__ part) {
  __shared__ unsigned h32[HBINS / 2];
  const int xb = blockIdx.x, job = blockIdx.y, sl = blockIdx.z;
  const int* arr = (job == 0) ? src_i : (job == 1) ? dst_i : (job == 2) ? src_b : dst_b;
  const int lo = sl * HBINS;
  for (int i = threadIdx.x; i < HBINS / 2; i += 256) h32[i] = 0;
  __syncthreads();
  const int4* a4 = (const int4*)(arr + xb * CHUNK);
  for (int q = threadIdx.x; q < CHUNK / 4; q += 256) {
    int4 v = a4[q];
    int t;
    t = v.x - lo; if ((unsigned)t < HBINS) atomicAdd(&h32[t >> 1], 1u << ((t & 1) * 16));
    t = v.y - lo; if ((unsigned)t < HBINS) atomicAdd(&h32[t >> 1], 1u << ((t & 1) * 16));
    t = v.z - lo; if ((unsigned)t < HBINS) atomicAdd(&h32[t >> 1], 1u << ((t & 1) * 16));
    t = v.w - lo; if ((unsigned)t < HBINS) atomicAdd(&h32[t >> 1], 1u << ((t & 1) * 16));
  }
  __syncthreads();
  unsigned short* dst = part + (size_t)(job * XB + xb) * N_NODES + lo;
  for (int i = threadIdx.x; i < HBINS; i += 256)
    dst[i] = (unsigned short)((h32[i >> 1] >> ((i & 1) * 16)) & 0xFFFFu);
}

// ---------------- reduce partials: degrees (+rsqrt) and in-place chunk prefixes ----
__global__ __launch_bounds__(256) void k_hred(
    unsigned short* __restrict__ part, int* __restrict__ cnt_di_i, int* __restrict__ cnt_di_b,
    float* __restrict__ dso_i, float* __restrict__ dsi_i,
    float* __restrict__ dso_b, float* __restrict__ dsi_b) {
  const int bin = blockIdx.x * 256 + threadIdx.x;
  if (bin >= N_NODES) return;
  int s;
  s = 0;
#pragma unroll
  for (int xb = 0; xb < XB; ++xb) s += part[(size_t)(0 * XB + xb) * N_NODES + bin];
  dso_i[bin] = rsqrtf((float)max(s, 1));
  s = 0;
#pragma unroll
  for (int xb = 0; xb < XB; ++xb) {
    size_t idx = (size_t)(1 * XB + xb) * N_NODES + bin;
    int v = part[idx];
    part[idx] = (unsigned short)s;
    s += v;
  }
  cnt_di_i[bin] = s;
  dsi_i[bin] = rsqrtf((float)max(s, 1));
  s = 0;
#pragma unroll
  for (int xb = 0; xb < XB; ++xb) s += part[(size_t)(2 * XB + xb) * N_NODES + bin];
  dso_b[bin] = rsqrtf((float)max(s, 1));
  s = 0;
#pragma unroll
  for (int xb = 0; xb < XB; ++xb) {
    size_t idx = (size_t)(3 * XB + xb) * N_NODES + bin;
    int v = part[idx];
    part[idx] = (unsigned short)s;
    s += v;
  }
  cnt_di_b[bin] = s;
  dsi_b[bin] = rsqrtf((float)max(s, 1));
}

// ---------------- scan phase 1: per-tile exclusive scan + tile totals ----------------
__global__ __launch_bounds__(256) void k_scan1(
    const int* __restrict__ cnt_i, const int* __restrict__ cnt_b,
    int* __restrict__ off_i, int* __restrict__ off_b, int* __restrict__ tsum) {
  const int rel = blockIdx.y;
  const int* cnt = rel ? cnt_b : cnt_i;
  int* off = rel ? off_b : off_i;
  const int tid = threadIdx.x;
  const int i0 = blockIdx.x * 1024 + tid * 4;
  int v[4];
#pragma unroll
  for (int k = 0; k < 4; ++k) v[k] = (i0 + k < N_NODES) ? cnt[i0 + k] : 0;
  int tl = v[0] + v[1] + v[2] + v[3];
  const int lane = tid & 63, wid = tid >> 6;
  int x = tl;
#pragma unroll
  for (int d = 1; d < 64; d <<= 1) {
    int t = __shfl_up(x, d);
    if (lane >= d) x += t;
  }
  __shared__ int wsum[4];
  if (lane == 63) wsum[wid] = x;
  __syncthreads();
  int wb = 0;
#pragma unroll
  for (int w = 0; w < 4; ++w)
    if (w < wid) wb += wsum[w];
  int run = wb + x - tl;
#pragma unroll
  for (int k = 0; k < 4; ++k) {
    if (i0 + k < N_NODES) off[i0 + k] = run;
    run += v[k];
  }
  if (tid == 255) tsum[rel * NT + blockIdx.x] = wb + x;
}

// ---------------- scan phase 2 ----------------
__global__ __launch_bounds__(256) void k_scan2(int* __restrict__ tsum) {
  __shared__ int a[256], b[256];
  const int t = threadIdx.x;
  for (int rel = 0; rel < 2; ++rel) {
    a[t] = (t < NT) ? tsum[rel * NT + t] : 0;
    __syncthreads();
    int* p = a;
    int* q = b;
    for (int d = 1; d < 256; d <<= 1) {
      q[t] = (t >= d) ? p[t - d] + p[t] : p[t];
      __syncthreads();
      int* tmp = p; p = q; q = tmp;
    }
    int excl = (t == 0) ? 0 : p[t - 1];
    if (t < NT) tsum[rel * NT + t] = excl;
    __syncthreads();
  }
}

// ---------------- scan phase 3 ----------------
__global__ __launch_bounds__(256) void k_scan3(
    const int* __restrict__ tsum, int* __restrict__ off_i, int* __restrict__ off_b) {
  const int rel = blockIdx.y;
  int* off = rel ? off_b : off_i;
  const int tb = tsum[rel * NT + blockIdx.x];
  const int i0 = blockIdx.x * 1024 + threadIdx.x * 4;
#pragma unroll
  for (int k = 0; k < 4; ++k)
    if (i0 + k < N_NODES) off[i0 + k] += tb;
  if (blockIdx.x == 0 && threadIdx.x == 0) off[N_NODES] = N_EDGES;
}

// ---------------- CSR fill: LDS cursors from exact reservations, NO global atomics ----
// grid (XB, 2, FSH). Slots [off[d]+pref[xb][d], +count) are disjoint across chunks.
__global__ __launch_bounds__(256) void k_fill(
    const int* __restrict__ src_i, const int* __restrict__ dst_i,
    const int* __restrict__ src_b, const int* __restrict__ dst_b,
    const int* __restrict__ off_i, const int* __restrict__ off_b,
    const unsigned short* __restrict__ part, int* __restrict__ es_i, int* __restrict__ es_b) {
  __shared__ int cur[FBINS];
  const int xb = blockIdx.x, rel = blockIdx.y, sl = blockIdx.z;
  const int* src = rel ? src_b : src_i;
  const int* dst = rel ? dst_b : dst_i;
  const int* off = rel ? off_b : off_i;
  int* es = rel ? es_b : es_i;
  const int lo = sl * FBINS;
  const unsigned short* pf = part + (size_t)((rel ? 3 : 1) * XB + xb) * N_NODES + lo;
  for (int i = threadIdx.x; i < FBINS; i += 256) cur[i] = off[lo + i] + pf[i];
  __syncthreads();
  const int4* s4p = (const int4*)(src + xb * CHUNK);
  const int4* d4p = (const int4*)(dst + xb * CHUNK);
  for (int q = threadIdx.x; q < CHUNK / 4; q += 256) {
    int4 d = d4p[q];
    int tx = d.x - lo, ty = d.y - lo, tz = d.z - lo, tw = d.w - lo;
    bool ax = (unsigned)tx < FBINS, ay = (unsigned)ty < FBINS,
         az = (unsigned)tz < FBINS, aw = (unsigned)tw < FBINS;
    if (!(ax | ay | az | aw)) continue;
    int4 s = s4p[q];
    if (ax) es[atomicAdd(&cur[tx], 1)] = s.x;
    if (ay) es[atomicAdd(&cur[ty], 1)] = s.y;
    if (az) es[atomicAdd(&cur[tz], 1)] = s.z;
    if (aw) es[atomicAdd(&cur[tw], 1)] = s.w;
  }
}

// ---------------- MFMA GEMM: C_fp16[row] = fp16( rs[row] * (A_f32[row] @ W_f32) ) ----
// 128 rows/block, 4 waves x (2 row-frags x 8 col-frags), K=128 in 4 chunks of 32.
// A-fragments read straight from global (row=lane&15, k=(lane>>4)*8+i, contiguous 32B).
// W staged transposed in LDS: shw[col][k], leading dim 136 halves.
// grid.y selects {Wa,rsa,Ca} / {Wb,rsb,Cb} (layer-1 dual pass reads A from HBM once).
__global__ __launch_bounds__(256) void k_gemm_mfma(
    const float* __restrict__ A,
    const float* __restrict__ Wa, const float* __restrict__ Wb,
    const float* __restrict__ rsa, const float* __restrict__ rsb,
    unsigned short* __restrict__ Ca, unsigned short* __restrict__ Cb) {
  __shared__ unsigned short shw[128 * WT_LD];  // 34 KB
  const int rel = blockIdx.y;
  const float* W = rel ? Wb : Wa;
  const float* rs = rel ? rsb : rsa;
  unsigned short* C = rel ? Cb : Ca;

  // stage W^T as fp16: task t -> c4 = t&31 (4 cols), kp = t>>5 (2 k's)
  for (int t = threadIdx.x; t < 2048; t += 256) {
    int c4 = (t & 31) * 4;
    int k = (t >> 5) * 2;
    float4 w0 = *(const float4*)&W[k * 128 + c4];
    float4 w1 = *(const float4*)&W[(k + 1) * 128 + c4];
    *(unsigned*)&shw[(c4 + 0) * WT_LD + k] = packh2(w0.x, w1.x);
    *(unsigned*)&shw[(c4 + 1) * WT_LD + k] = packh2(w0.y, w1.y);
    *(unsigned*)&shw[(c4 + 2) * WT_LD + k] = packh2(w0.z, w1.z);
    *(unsigned*)&shw[(c4 + 3) * WT_LD + k] = packh2(w0.w, w1.w);
  }
  __syncthreads();

  const int w = threadIdx.x >> 6;     // wave 0..3
  const int l = threadIdx.x & 63;     // lane
  const int lc = l & 15;              // col-in-frag / row-in-frag
  const int lk = l >> 4;              // k-group 0..3
  const int rb = blockIdx.x * 128 + w * 32;  // this wave's first row

  f32x4 acc[2][8];
#pragma unroll
  for (int rf = 0; rf < 2; ++rf)
#pragma unroll
    for (int cf = 0; cf < 8; ++cf) acc[rf][cf] = (f32x4)(0.f);

  union H8 { unsigned u[4]; half8_t h; };

#pragma unroll
  for (int kc = 0; kc < 4; ++kc) {
    const int kbase = kc * 32 + lk * 8;
    H8 a[2];
#pragma unroll
    for (int rf = 0; rf < 2; ++rf) {
      int row = rb + rf * 16 + lc;
      row = min(row, N_NODES - 1);  // clamp (stores guarded)
      const float4* ap = (const float4*)(A + (size_t)row * 128 + kbase);
      float4 f0 = ap[0], f1 = ap[1];
      a[rf].u[0] = packh2(f0.x, f0.y);
      a[rf].u[1] = packh2(f0.z, f0.w);
      a[rf].u[2] = packh2(f1.x, f1.y);
      a[rf].u[3] = packh2(f1.z, f1.w);
    }
#pragma unroll
    for (int cf = 0; cf < 8; ++cf) {
      half8_t b = *(const half8_t*)&shw[(cf * 16 + lc) * WT_LD + kbase];
      acc[0][cf] = __builtin_amdgcn_mfma_f32_16x16x32_f16(a[0].h, b, acc[0][cf], 0, 0, 0);
      acc[1][cf] = __builtin_amdgcn_mfma_f32_16x16x32_f16(a[1].h, b, acc[1][cf], 0, 0, 0);
    }
  }

  // epilogue: D row = (lane>>4)*4 + reg, col = cf*16 + (lane&15)
#pragma unroll
  for (int rf = 0; rf < 2; ++rf) {
#pragma unroll
    for (int reg = 0; reg < 4; ++reg) {
      int row = rb + rf * 16 + lk * 4 + reg;
      if (row < N_NODES) {
        float s = rs[row];
        unsigned short* crow = C + (size_t)row * 128 + lc;
#pragma unroll
        for (int cf = 0; cf < 8; ++cf) {
          __half h = __float2half_rn(acc[rf][cf][reg] * s);
          crow[cf * 16] = *(unsigned short*)&h;
        }
      }
    }
  }
}

// ---------------- SpMM: 16 lanes/node (uint4 = 8 fp16 cols each), 16 nodes/block ----
// MODE 0: out = relu(agg*dsi + b); MODE 1: out += relu(...); MODE 2: out = agg*dsi + b
template <int MODE>
__global__ __launch_bounds__(256) void k_spmm(
    const unsigned short* __restrict__ Xh, const int* __restrict__ off,
    const int* __restrict__ srcs, const float* __restrict__ dsi,
    const float* __restrict__ bias, float* __restrict__ out) {
  const int g = threadIdx.x >> 4;  // node group
  const int l = threadIdx.x & 15;  // lane: 8 cols
  const int n = blockIdx.x * 16 + g;
  if (n >= N_NODES) return;
  const int e0 = off[n];
  const int e1 = off[n + 1];
  const uint4* Xv = (const uint4*)Xh;  // row = 16 uint4
  float a0 = 0.f, a1 = 0.f, a2 = 0.f, a3 = 0.f, a4 = 0.f, a5 = 0.f, a6 = 0.f, a7 = 0.f;
  for (int eb = e0; eb < e1; eb += 16) {
    int idx = eb + l;
    int s = (idx < e1) ? srcs[idx] : 0;
    int cnt = min(16, e1 - eb);
#pragma unroll 4
    for (int j = 0; j < cnt; ++j) {
      int sj = __shfl(s, j, 16);
      uint4 v = Xv[(size_t)sj * 16 + l];
      float2 f;
      f = __half22float2(*(__half2*)&v.x); a0 += f.x; a1 += f.y;
      f = __half22float2(*(__half2*)&v.y); a2 += f.x; a3 += f.y;
      f = __half22float2(*(__half2*)&v.z); a4 += f.x; a5 += f.y;
      f = __half22float2(*(__half2*)&v.w); a6 += f.x; a7 += f.y;
    }
  }
  const float dn = dsi[n];
  float4 b0 = ((const float4*)bias)[l * 2];
  float4 b1 = ((const float4*)bias)[l * 2 + 1];
  float4 y0, y1;
  y0.x = fmaf(a0, dn, b0.x); y0.y = fmaf(a1, dn, b0.y);
  y0.z = fmaf(a2, dn, b0.z); y0.w = fmaf(a3, dn, b0.w);
  y1.x = fmaf(a4, dn, b1.x); y1.y = fmaf(a5, dn, b1.y);
  y1.z = fmaf(a6, dn, b1.z); y1.w = fmaf(a7, dn, b1.w);
  if (MODE != 2) {
    y0.x = fmaxf(y0.x, 0.f); y0.y = fmaxf(y0.y, 0.f);
    y0.z = fmaxf(y0.z, 0.f); y0.w = fmaxf(y0.w, 0.f);
    y1.x = fmaxf(y1.x, 0.f); y1.y = fmaxf(y1.y, 0.f);
    y1.z = fmaxf(y1.z, 0.f); y1.w = fmaxf(y1.w, 0.f);
  }
  float4* ov = (float4*)out;
  size_t oi = (size_t)n * 32 + l * 2;
  if (MODE == 1) {
    float4 p0 = ov[oi], p1 = ov[oi + 1];
    y0.x += p0.x; y0.y += p0.y; y0.z += p0.z; y0.w += p0.w;
    y1.x += p1.x; y1.y += p1.y; y1.z += p1.z; y1.w += p1.w;
  }
  ov[oi] = y0;
  ov[oi + 1] = y1;
}

// ---------------- host ----------------
extern "C" void kernel_launch(void* const* d_in, const int* in_sizes, int n_in,
                              void* d_out, int out_size, void* d_ws, size_t ws_size,
                              hipStream_t stream) {
  const float* x    = (const float*)d_in[0];
  const int* src_i  = (const int*)d_in[1];
  const int* dst_i  = (const int*)d_in[2];
  const int* src_b  = (const int*)d_in[3];
  const int* dst_b  = (const int*)d_in[4];
  const float* W1_i = (const float*)d_in[5];
  const float* b1_i = (const float*)d_in[6];
  const float* W1_b = (const float*)d_in[7];
  const float* b1_b = (const float*)d_in[8];
  const float* W2   = (const float*)d_in[9];
  const float* b2   = (const float*)d_in[10];
  float* out = (float*)d_out;

  char* ws = (char*)d_ws;
  size_t o = 0;
  auto alloc = [&](size_t bytes) {
    char* p = ws + o;
    o += (bytes + 255) & ~(size_t)255;
    return p;
  };
  float* dso_i = (float*)alloc(N_NODES * 4);
  float* dsi_i = (float*)alloc(N_NODES * 4);
  float* dso_b = (float*)alloc(N_NODES * 4);
  float* dsi_b = (float*)alloc(N_NODES * 4);
  int* cnt_di_i = (int*)alloc(N_NODES * 4);
  int* cnt_di_b = (int*)alloc(N_NODES * 4);
  int* off_i = (int*)alloc((N_NODES + 1) * 4);
  int* off_b = (int*)alloc((N_NODES + 1) * 4);
  int* tsum = (int*)alloc(2 * NT * 4);
  int* es_i = (int*)alloc((size_t)N_EDGES * 4);
  int* es_b = (int*)alloc((size_t)N_EDGES * 4);
  // union region (51.2 MB): part (u16, 4*XB*N*2 = 25.6 MB) is dead before the
  // first GEMM; buf_i (fp16, 25.6 MB) aliases it and buf_b sits above it.
  char* uni = alloc((size_t)2 * N_NODES * 128 * 2);
  unsigned short* part  = (unsigned short*)uni;
  unsigned short* buf_i = (unsigned short*)uni;
  unsigned short* buf_b = (unsigned short*)(uni + (size_t)N_NODES * 128 * 2);
  (void)ws_size; (void)in_sizes; (void)n_in; (void)out_size;

  k_hist<<<dim3(XB, 4, HSH), dim3(256), 0, stream>>>(src_i, dst_i, src_b, dst_b, part);
  k_hred<<<(N_NODES + 255) / 256, dim3(256), 0, stream>>>(
      part, cnt_di_i, cnt_di_b, dso_i, dsi_i, dso_b, dsi_b);
  k_scan1<<<dim3(NT, 2), dim3(256), 0, stream>>>(cnt_di_i, cnt_di_b, off_i, off_b, tsum);
  k_scan2<<<1, 256, 0, stream>>>(tsum);
  k_scan3<<<dim3(NT, 2), dim3(256), 0, stream>>>(tsum, off_i, off_b);
  k_fill<<<dim3(XB, 2, FSH), dim3(256), 0, stream>>>(
      src_i, dst_i, src_b, dst_b, off_i, off_b, part, es_i, es_b);

  const int ggrid = (N_NODES + 127) / 128;  // 782
  const int sgrid = (N_NODES + 15) / 16;
  // conv1: both relations in one pass (x read once)
  k_gemm_mfma<<<dim3(ggrid, 2), dim3(256), 0, stream>>>(
      x, W1_i, W1_b, dso_i, dso_b, buf_i, buf_b);
  k_spmm<0><<<sgrid, 256, 0, stream>>>(buf_i, off_i, es_i, dsi_i, b1_i, out);
  k_spmm<1><<<sgrid, 256, 0, stream>>>(buf_b, off_b, es_b, dsi_b, b1_b, out);
  // conv2 / interacts (no relu)
  k_gemm_mfma<<<dim3(ggrid, 1), dim3(256), 0, stream>>>(
      out, W2, W2, dso_i, dso_i, buf_i, buf_i);
  k_spmm<2><<<sgrid, 256, 0, stream>>>(buf_i, off_i, es_i, dsi_i, b2, out);
}